// Round 6
// baseline (1722.576 us; speedup 1.0000x reference)
//
#include <hip/hip_runtime.h>

#define NN 50000
#define NE 800000

// ---------------- CSR build ----------------
__global__ __launch_bounds__(256) void init_int_kernel(int* __restrict__ a, int n) {
  int i = blockIdx.x * 256 + threadIdx.x;
  if (i < n) a[i] = 0;
}

// edge_index arrives as int32 (harness converts integer inputs to int32).
// Clamp defensively: a bad index becomes a wrong answer, not a page fault.
__global__ __launch_bounds__(256) void hist_kernel(const int* __restrict__ ei,
                                                   int* __restrict__ deg) {
  int e = blockIdx.x * 256 + threadIdx.x;
  if (e < NE) {
    int d = ei[NE + e];
    if ((unsigned)d >= NN) d = 0;
    atomicAdd(&deg[d], 1);
  }
}

__global__ __launch_bounds__(1024) void scan_kernel(const int* __restrict__ deg,
                                                    int* __restrict__ offs) {
  __shared__ int part[1024];
  int tid = threadIdx.x;
  const int chunk = (NN + 1023) / 1024;  // 49
  int base = tid * chunk;
  int s = 0;
  for (int j = 0; j < chunk; ++j) {
    int idx = base + j;
    if (idx < NN) s += deg[idx];
  }
  part[tid] = s;
  __syncthreads();
  for (int off = 1; off < 1024; off <<= 1) {
    int t = (tid >= off) ? part[tid - off] : 0;
    __syncthreads();
    part[tid] += t;
    __syncthreads();
  }
  int run = (tid > 0) ? part[tid - 1] : 0;
  for (int j = 0; j < chunk; ++j) {
    int idx = base + j;
    if (idx < NN) { offs[idx] = run; run += deg[idx]; }
  }
  if (tid == 1023) offs[NN] = part[1023];
}

__global__ __launch_bounds__(256) void scatter_kernel(const int* __restrict__ ei,
    const int* __restrict__ offs, int* __restrict__ cursor,
    int* __restrict__ csr_eid, int* __restrict__ csr_src) {
  int e = blockIdx.x * 256 + threadIdx.x;
  if (e < NE) {
    int s = ei[e];
    int d = ei[NE + e];
    if ((unsigned)s >= NN) s = 0;
    if ((unsigned)d >= NN) d = 0;
    int pos = atomicAdd(&cursor[d], 1);
    int slot = offs[d] + pos;
    csr_eid[slot] = e;
    csr_src[slot] = s;
  }
}

// ---------------- node projections: q(=*0.25), k, v, skipx = x@Wskip+bskip+x ----
__global__ __launch_bounds__(256) void node_proj_kernel(
    const float* __restrict__ x,
    const float* __restrict__ Wq, const float* __restrict__ bq,
    const float* __restrict__ Wk, const float* __restrict__ bk,
    const float* __restrict__ Wv, const float* __restrict__ bv,
    const float* __restrict__ Wsk, const float* __restrict__ bsk,
    float* __restrict__ qo, float* __restrict__ ko, float* __restrict__ vo,
    float* __restrict__ so) {
  __shared__ float xs[64 * 128];
  int tid = threadIdx.x;
  int row0 = blockIdx.x * 64;
  int nrows = NN - row0; if (nrows > 64) nrows = 64;
  const float4* xg = (const float4*)(x + (size_t)row0 * 128);
  float4* xs4 = (float4*)xs;
  int nv = nrows * 32;
  for (int i = tid; i < 64 * 32; i += 256)
    if (i < nv) xs4[i] = xg[i];
  __syncthreads();

  int colg = tid & 31;   // cols colg*4..+3
  int rowg = tid >> 5;   // rows rowg*8..+7
  const float* Wm[4] = {Wq, Wk, Wv, Wsk};
  const float* bm[4] = {bq, bk, bv, bsk};
  float* om[4] = {qo, ko, vo, so};

  for (int m = 0; m < 4; ++m) {
    const float* W = Wm[m];
    float acc[8][4];
    #pragma unroll
    for (int r = 0; r < 8; ++r)
      #pragma unroll
      for (int c = 0; c < 4; ++c) acc[r][c] = 0.f;
    for (int k0 = 0; k0 < 128; k0 += 4) {
      float4 w0 = *(const float4*)(W + (size_t)(k0 + 0) * 128 + colg * 4);
      float4 w1 = *(const float4*)(W + (size_t)(k0 + 1) * 128 + colg * 4);
      float4 w2 = *(const float4*)(W + (size_t)(k0 + 2) * 128 + colg * 4);
      float4 w3 = *(const float4*)(W + (size_t)(k0 + 3) * 128 + colg * 4);
      #pragma unroll
      for (int r = 0; r < 8; ++r) {
        float4 xv = *(const float4*)(&xs[(rowg * 8 + r) * 128 + k0]);
        acc[r][0] += xv.x * w0.x + xv.y * w1.x + xv.z * w2.x + xv.w * w3.x;
        acc[r][1] += xv.x * w0.y + xv.y * w1.y + xv.z * w2.y + xv.w * w3.y;
        acc[r][2] += xv.x * w0.z + xv.y * w1.z + xv.z * w2.z + xv.w * w3.z;
        acc[r][3] += xv.x * w0.w + xv.y * w1.w + xv.z * w2.w + xv.w * w3.w;
      }
    }
    float4 bb = *(const float4*)(bm[m] + colg * 4);
    float* outp = om[m];
    #pragma unroll
    for (int r = 0; r < 8; ++r) {
      int lr = rowg * 8 + r;
      if (lr < nrows) {
        float4 res;
        res.x = acc[r][0] + bb.x;
        res.y = acc[r][1] + bb.y;
        res.z = acc[r][2] + bb.z;
        res.w = acc[r][3] + bb.w;
        if (m == 0) { res.x *= 0.25f; res.y *= 0.25f; res.z *= 0.25f; res.w *= 0.25f; }
        if (m == 3) {
          res.x += xs[lr * 128 + colg * 4 + 0];
          res.y += xs[lr * 128 + colg * 4 + 1];
          res.z += xs[lr * 128 + colg * 4 + 2];
          res.w += xs[lr * 128 + colg * 4 + 3];
        }
        *(float4*)(outp + (size_t)(row0 + lr) * 128 + colg * 4) = res;
      }
    }
  }
}

// ---------------- qe[n,h,j] = sum_c q_scaled[n,h,c] * We[j, h*16+c] ----------
__global__ __launch_bounds__(256) void qe_kernel(const float* __restrict__ q,
                                                 const float* __restrict__ We,
                                                 float* __restrict__ qe) {
  long idx = (long)blockIdx.x * 256 + threadIdx.x;  // N*512 total
  int n = (int)(idx >> 9);
  int r = (int)(idx & 511);
  int h = r >> 6, j = r & 63;
  const float* qp = q + (size_t)n * 128 + h * 16;
  const float* wp = We + (size_t)j * 128 + h * 16;
  float s = 0.f;
  #pragma unroll
  for (int c = 0; c < 16; ++c) s += qp[c] * wp[c];
  qe[idx] = s;
}

// ---------------- per-node attention + LN1 -> hbuf ----------------
// One wave per node. Lane roles:
//   logits phase: edge group g = lane>>3, head hh = lane&7
//   accum phase:  output elems (2*lane, 2*lane+1), owned head = lane>>3,
//                 wea j-slice = (lane&7)*8..+8
__global__ __launch_bounds__(256) void agg_ln1_kernel(
    const float* __restrict__ q, const float* __restrict__ kb,
    const float* __restrict__ vb, const float* __restrict__ qe,
    const float* __restrict__ ea, const float* __restrict__ skipx,
    const float* __restrict__ We,
    const int* __restrict__ offs, const int* __restrict__ csr_eid,
    const int* __restrict__ csr_src,
    const float* __restrict__ g1, const float* __restrict__ b1,
    float* __restrict__ hbuf) {
  __shared__ float ea_s[4][8][68];   // +4 pad breaks bank collisions
  __shared__ float wea_s[4][8][68];
  int tid = threadIdx.x;
  int wave = tid >> 6;
  int lane = tid & 63;
  int node = blockIdx.x * 4 + wave;
  float (*eas)[68] = ea_s[wave];
  float (*weas)[68] = wea_s[wave];

  int g = lane >> 3;
  int hh = lane & 7;

  float q_r[16];
  {
    const float* qp = q + (size_t)node * 128 + hh * 16;
    #pragma unroll
    for (int u = 0; u < 4; ++u) {
      float4 t = *(const float4*)(qp + 4 * u);
      q_r[4*u+0] = t.x; q_r[4*u+1] = t.y; q_r[4*u+2] = t.z; q_r[4*u+3] = t.w;
    }
  }
  float qe_r[64];
  {
    const float* qp = qe + (size_t)node * 512 + hh * 64;
    #pragma unroll
    for (int u = 0; u < 16; ++u) {
      float4 t = *(const float4*)(qp + 4 * u);
      qe_r[4*u+0] = t.x; qe_r[4*u+1] = t.y; qe_r[4*u+2] = t.z; qe_r[4*u+3] = t.w;
    }
  }
  float wea_r[8];
  #pragma unroll
  for (int j = 0; j < 8; ++j) wea_r[j] = 0.f;
  float wv0 = 0.f, wv1 = 0.f, pden = 0.f;

  int base = offs[node];
  int deg = offs[node + 1] - base;

  for (int t0 = 0; t0 < deg; t0 += 8) {
    int myi = t0 + g;
    int valid = myi < deg;
    int slot = base + (valid ? myi : 0);
    int eid = csr_eid[slot];
    int src = csr_src[slot];

    // stage edge_attr rows for 8 edges (lane stages floats hh*8..+8 of edge g)
    const float4* eap = (const float4*)(ea + (size_t)eid * 64);
    float4 a0 = eap[hh * 2];
    float4 a1 = eap[hh * 2 + 1];
    *(float4*)(&eas[g][hh * 8]) = a0;
    *(float4*)(&eas[g][hh * 8 + 4]) = a1;
    asm volatile("s_waitcnt lgkmcnt(0)" ::: "memory");  // same-wave LDS visibility

    // logit for (edge g, head hh): q.k + qe.ea  (q pre-scaled by 1/sqrt(C))
    const float* kp = kb + (size_t)src * 128 + hh * 16;
    float lg = 0.f;
    #pragma unroll
    for (int u = 0; u < 4; ++u) {
      float4 kv = *(const float4*)(kp + 4 * u);
      lg += q_r[4*u+0]*kv.x + q_r[4*u+1]*kv.y + q_r[4*u+2]*kv.z + q_r[4*u+3]*kv.w;
    }
    #pragma unroll
    for (int u = 0; u < 16; ++u) {
      float4 av = *(const float4*)(&eas[g][4 * u]);
      lg += qe_r[4*u+0]*av.x + qe_r[4*u+1]*av.y + qe_r[4*u+2]*av.z + qe_r[4*u+3]*av.w;
    }
    float w = valid ? __expf(lg) : 0.f;  // logits bounded ~|2.5|; shift-free softmax
    pden += w;

    // accumulate: wv (elems 2*lane,2*lane+1 of head lane>>3==g) and wea slice
    #pragma unroll
    for (int g2 = 0; g2 < 8; ++g2) {
      int   sg  = __shfl(src, g2 * 8, 64);
      float wgh = __shfl(w, g2 * 8 + g, 64);  // w[edge g2][head lane>>3]
      float2 vv = *(const float2*)(vb + (size_t)sg * 128 + lane * 2);
      wv0 += wgh * vv.x;
      wv1 += wgh * vv.y;
      float4 e0 = *(const float4*)(&eas[g2][hh * 8]);
      float4 e1 = *(const float4*)(&eas[g2][hh * 8 + 4]);
      wea_r[0] += wgh * e0.x; wea_r[1] += wgh * e0.y;
      wea_r[2] += wgh * e0.z; wea_r[3] += wgh * e0.w;
      wea_r[4] += wgh * e1.x; wea_r[5] += wgh * e1.y;
      wea_r[6] += wgh * e1.z; wea_r[7] += wgh * e1.w;
    }
    asm volatile("s_waitcnt lgkmcnt(0)" ::: "memory");  // reads done before next stage
  }

  // denom: reduce partials over edge-groups (xor bits 3..5), then fetch for owned head
  float den = pden;
  den += __shfl_xor(den, 8, 64);
  den += __shfl_xor(den, 16, 64);
  den += __shfl_xor(den, 32, 64);
  float denf = __shfl(den, g, 64);  // lanes 0..7 hold denom[head 0..7]

  // wea -> LDS, then per-node (wea @ We) for this lane's two output elems
  *(float4*)(&weas[g][hh * 8])     = make_float4(wea_r[0], wea_r[1], wea_r[2], wea_r[3]);
  *(float4*)(&weas[g][hh * 8 + 4]) = make_float4(wea_r[4], wea_r[5], wea_r[6], wea_r[7]);
  asm volatile("s_waitcnt lgkmcnt(0)" ::: "memory");

  float s0 = wv0, s1 = wv1;
  const float* wep = We + lane * 2;
  #pragma unroll
  for (int u = 0; u < 16; ++u) {
    float4 ww = *(const float4*)(&weas[g][4 * u]);
    float2 p0 = *(const float2*)(wep + (size_t)(4 * u + 0) * 128);
    float2 p1 = *(const float2*)(wep + (size_t)(4 * u + 1) * 128);
    float2 p2 = *(const float2*)(wep + (size_t)(4 * u + 2) * 128);
    float2 p3 = *(const float2*)(wep + (size_t)(4 * u + 3) * 128);
    s0 += ww.x * p0.x + ww.y * p1.x + ww.z * p2.x + ww.w * p3.x;
    s1 += ww.x * p0.y + ww.y * p1.y + ww.z * p2.y + ww.w * p3.y;
  }
  float inv = (deg > 0) ? 1.f / denf : 0.f;
  float2 skv = *(const float2*)(skipx + (size_t)node * 128 + lane * 2);
  float c0 = s0 * inv + skv.x;
  float c1 = s1 * inv + skv.y;

  // LN1 across 128 elems (2 per lane)
  float sum = c0 + c1;
  float sq = c0 * c0 + c1 * c1;
  #pragma unroll
  for (int o = 1; o < 64; o <<= 1) {
    sum += __shfl_xor(sum, o, 64);
    sq  += __shfl_xor(sq, o, 64);
  }
  float mean = sum * (1.f / 128.f);
  float var = sq * (1.f / 128.f) - mean * mean;
  float rstd = rsqrtf(var + 1e-5f);
  float2 gg = *(const float2*)(g1 + lane * 2);
  float2 bb = *(const float2*)(b1 + lane * 2);
  float h0 = (c0 - mean) * rstd * gg.x + bb.x;
  float h1 = (c1 - mean) * rstd * gg.y + bb.y;
  // NOTE: hbuf aliases skipx (safe: each lane reads skipx[node] above, then
  // writes the same addresses; no cross-node access in this kernel).
  *(float2*)(hbuf + (size_t)node * 128 + lane * 2) = make_float2(h0, h1);
}

// ---------------- FFN (gelu-erf) + residual + LN2 -> out ----------------
__global__ __launch_bounds__(256) void ffn_ln2_kernel(
    const float* __restrict__ hbuf,
    const float* __restrict__ Wf1, const float* __restrict__ bf1,
    const float* __restrict__ Wf2, const float* __restrict__ bf2,
    const float* __restrict__ g2v, const float* __restrict__ b2v,
    float* __restrict__ out) {
  __shared__ float hs[16 * 128];
  __shared__ float ts[16][516];  // +4 pad
  int tid = threadIdx.x;
  size_t row0 = (size_t)blockIdx.x * 16;
  const float4* hg = (const float4*)(hbuf + row0 * 128);
  float4* hs4 = (float4*)hs;
  hs4[tid] = hg[tid];
  hs4[tid + 256] = hg[tid + 256];
  __syncthreads();

  {  // GEMM1: t[16][512] = gelu(h @ Wf1 + bf1)
    int colg = tid & 63;   // cols colg*8..+7
    int rowq = tid >> 6;   // rows rowq*4..+3
    float acc[4][8];
    #pragma unroll
    for (int r = 0; r < 4; ++r)
      #pragma unroll
      for (int c = 0; c < 8; ++c) acc[r][c] = 0.f;
    for (int k0 = 0; k0 < 128; k0 += 4) {
      float hva[4][4];
      #pragma unroll
      for (int r = 0; r < 4; ++r) {
        float4 t = *(const float4*)(&hs[(rowq * 4 + r) * 128 + k0]);
        hva[r][0] = t.x; hva[r][1] = t.y; hva[r][2] = t.z; hva[r][3] = t.w;
      }
      #pragma unroll
      for (int kd = 0; kd < 4; ++kd) {
        float4 w0 = *(const float4*)(Wf1 + (size_t)(k0 + kd) * 512 + colg * 8);
        float4 w1 = *(const float4*)(Wf1 + (size_t)(k0 + kd) * 512 + colg * 8 + 4);
        #pragma unroll
        for (int r = 0; r < 4; ++r) {
          float hv = hva[r][kd];
          acc[r][0] += hv * w0.x; acc[r][1] += hv * w0.y;
          acc[r][2] += hv * w0.z; acc[r][3] += hv * w0.w;
          acc[r][4] += hv * w1.x; acc[r][5] += hv * w1.y;
          acc[r][6] += hv * w1.z; acc[r][7] += hv * w1.w;
        }
      }
    }
    float4 bb0 = *(const float4*)(bf1 + colg * 8);
    float4 bb1 = *(const float4*)(bf1 + colg * 8 + 4);
    float bba[8] = {bb0.x, bb0.y, bb0.z, bb0.w, bb1.x, bb1.y, bb1.z, bb1.w};
    #pragma unroll
    for (int r = 0; r < 4; ++r) {
      #pragma unroll
      for (int c = 0; c < 8; ++c) {
        float val = acc[r][c] + bba[c];
        val = 0.5f * val * (1.f + erff(val * 0.70710678118654752440f));
        ts[rowq * 4 + r][colg * 8 + c] = val;
      }
    }
  }
  __syncthreads();
  {  // GEMM2 + residual + LN2
    int row = tid >> 4;   // 16 rows
    int cg = tid & 15;    // cols cg*8..+7
    float f[8];
    #pragma unroll
    for (int c = 0; c < 8; ++c) f[c] = 0.f;
    for (int k0 = 0; k0 < 512; k0 += 4) {
      float4 tt = *(const float4*)(&ts[row][k0]);
      float tva[4] = {tt.x, tt.y, tt.z, tt.w};
      #pragma unroll
      for (int kd = 0; kd < 4; ++kd) {
        float4 w0 = *(const float4*)(Wf2 + (size_t)(k0 + kd) * 128 + cg * 8);
        float4 w1 = *(const float4*)(Wf2 + (size_t)(k0 + kd) * 128 + cg * 8 + 4);
        float tv = tva[kd];
        f[0] += tv * w0.x; f[1] += tv * w0.y; f[2] += tv * w0.z; f[3] += tv * w0.w;
        f[4] += tv * w1.x; f[5] += tv * w1.y; f[6] += tv * w1.z; f[7] += tv * w1.w;
      }
    }
    float4 bb0 = *(const float4*)(bf2 + cg * 8);
    float4 bb1 = *(const float4*)(bf2 + cg * 8 + 4);
    float4 h0 = *(const float4*)(&hs[row * 128 + cg * 8]);
    float4 h1 = *(const float4*)(&hs[row * 128 + cg * 8 + 4]);
    f[0] += bb0.x + h0.x; f[1] += bb0.y + h0.y; f[2] += bb0.z + h0.z; f[3] += bb0.w + h0.w;
    f[4] += bb1.x + h1.x; f[5] += bb1.y + h1.y; f[6] += bb1.z + h1.z; f[7] += bb1.w + h1.w;

    float sum = 0.f, sq = 0.f;
    #pragma unroll
    for (int c = 0; c < 8; ++c) { sum += f[c]; sq += f[c] * f[c]; }
    #pragma unroll
    for (int o = 1; o < 16; o <<= 1) {
      sum += __shfl_xor(sum, o, 64);
      sq  += __shfl_xor(sq, o, 64);
    }
    float mean = sum * (1.f / 128.f);
    float var = sq * (1.f / 128.f) - mean * mean;
    float rstd = rsqrtf(var + 1e-5f);
    float4 gg0 = *(const float4*)(g2v + cg * 8);
    float4 gg1 = *(const float4*)(g2v + cg * 8 + 4);
    float4 vb0 = *(const float4*)(b2v + cg * 8);
    float4 vb1 = *(const float4*)(b2v + cg * 8 + 4);
    float4 o0, o1;
    o0.x = (f[0] - mean) * rstd * gg0.x + vb0.x;
    o0.y = (f[1] - mean) * rstd * gg0.y + vb0.y;
    o0.z = (f[2] - mean) * rstd * gg0.z + vb0.z;
    o0.w = (f[3] - mean) * rstd * gg0.w + vb0.w;
    o1.x = (f[4] - mean) * rstd * gg1.x + vb1.x;
    o1.y = (f[5] - mean) * rstd * gg1.y + vb1.y;
    o1.z = (f[6] - mean) * rstd * gg1.z + vb1.z;
    o1.w = (f[7] - mean) * rstd * gg1.w + vb1.w;
    float* op = out + (row0 + row) * 128 + cg * 8;
    *(float4*)op = o0;
    *(float4*)(op + 4) = o1;
  }
}

extern "C" void kernel_launch(void* const* d_in, const int* in_sizes, int n_in,
                              void* d_out, int out_size, void* d_ws, size_t ws_size,
                              hipStream_t stream) {
  const float* x   = (const float*)d_in[0];
  const int* ei    = (const int*)d_in[1];      // int32 on device (harness converts)
  const float* ea  = (const float*)d_in[2];
  const float* Wq  = (const float*)d_in[3];  const float* bq  = (const float*)d_in[4];
  const float* Wk  = (const float*)d_in[5];  const float* bk  = (const float*)d_in[6];
  const float* Wv  = (const float*)d_in[7];  const float* bv  = (const float*)d_in[8];
  const float* We  = (const float*)d_in[9];
  const float* Wsk = (const float*)d_in[10]; const float* bsk = (const float*)d_in[11];
  const float* g1  = (const float*)d_in[12]; const float* b1  = (const float*)d_in[13];
  const float* g2  = (const float*)d_in[14]; const float* b2  = (const float*)d_in[15];
  const float* Wf1 = (const float*)d_in[16]; const float* bf1 = (const float*)d_in[17];
  const float* Wf2 = (const float*)d_in[18]; const float* bf2 = (const float*)d_in[19];
  float* outp = (float*)d_out;

  char* w = (char*)d_ws;
  float* qb   = (float*)w; w += (size_t)NN * 128 * 4;
  float* kb   = (float*)w; w += (size_t)NN * 128 * 4;
  float* vb   = (float*)w; w += (size_t)NN * 128 * 4;
  float* sk   = (float*)w; w += (size_t)NN * 128 * 4;
  float* hb   = sk;  // alias: agg_ln1 reads skipx[node] before writing hbuf[node]
  float* qeb  = (float*)w; w += (size_t)NN * 512 * 4;
  int* deg    = (int*)w;   w += (size_t)NN * 4;
  int* cursor = (int*)w;   w += (size_t)NN * 4;
  int* offs   = (int*)w;   w += (size_t)(NN + 1) * 4;
  int* ceid   = (int*)w;   w += (size_t)NE * 4;
  int* csrc   = (int*)w;   w += (size_t)NE * 4;

  init_int_kernel<<<(2 * NN + 255) / 256, 256, 0, stream>>>(deg, 2 * NN);  // deg+cursor contiguous
  hist_kernel<<<NE / 256, 256, 0, stream>>>(ei, deg);
  scan_kernel<<<1, 1024, 0, stream>>>(deg, offs);
  scatter_kernel<<<NE / 256, 256, 0, stream>>>(ei, offs, cursor, ceid, csrc);
  node_proj_kernel<<<(NN + 63) / 64, 256, 0, stream>>>(x, Wq, bq, Wk, bk, Wv, bv, Wsk, bsk,
                                                       qb, kb, vb, sk);
  qe_kernel<<<NN * 2, 256, 0, stream>>>(qb, We, qeb);
  agg_ln1_kernel<<<NN / 4, 256, 0, stream>>>(qb, kb, vb, qeb, ea, sk, We,
                                             offs, ceid, csrc, g1, b1, hb);
  ffn_ln2_kernel<<<NN / 16, 256, 0, stream>>>(hb, Wf1, bf1, Wf2, bf2, g2, b2, outp);
}